// Round 7
// baseline (188.471 us; speedup 1.0000x reference)
//
#include <hip/hip_runtime.h>
#include <hip/hip_bf16.h>
#include <cstdint>

#define DEV __device__ __forceinline__

typedef __attribute__((ext_vector_type(8))) __bf16 bf16x8;
typedef __attribute__((ext_vector_type(4))) float floatx4;
typedef __attribute__((ext_vector_type(4))) short shortx4;
typedef __attribute__((ext_vector_type(8))) short shortx8;

// 0.125 (= dim_head^-0.5) * log2(e): fold scale AND base-2 conversion into Q.
constexpr float QSCALE = 0.18033688011112042f;

DEV unsigned short f2b(float f) {
  union { float f; unsigned u; } v; v.f = f;
  return (unsigned short)((v.u + 0x7fffu + ((v.u >> 16) & 1u)) >> 16);  // RTNE
}

#if defined(__has_builtin) && __has_builtin(__builtin_amdgcn_cvt_pk_bf16_f32)
DEV unsigned pk2(float a, float b) {
  typedef __attribute__((ext_vector_type(2))) __bf16 bf2;
  union { bf2 v; unsigned u; } u;
  u.v = __builtin_amdgcn_cvt_pk_bf16_f32(a, b);
  return u.u;
}
#else
DEV unsigned pk2(float a, float b) {
  return (unsigned)f2b(a) | ((unsigned)f2b(b) << 16);
}
#endif

#if defined(__has_builtin) && __has_builtin(__builtin_amdgcn_exp2f)
DEV float fexp2(float x) { return __builtin_amdgcn_exp2f(x); }
#else
DEV float fexp2(float x) { return exp2f(x); }
#endif

DEV floatx4 mfma16(bf16x8 a, bf16x8 b, floatx4 c) {
  return __builtin_amdgcn_mfma_f32_16x16x32_bf16(a, b, c, 0, 0, 0);
}

#define GLD_LDS16(gp, lp)                                                          \
  __builtin_amdgcn_global_load_lds(                                                \
      (const __attribute__((address_space(1))) void*)(gp),                         \
      (__attribute__((address_space(3))) void*)(lp), 16, 0, 0)

// ---------------------------------------------------------------- conversions
__global__ void cvt_f32_bf16(const float* __restrict__ in,
                             unsigned short* __restrict__ out, int n4) {
  int i = blockIdx.x * 256 + threadIdx.x;
  if (i >= n4) return;
  floatx4 f = ((const floatx4*)in)[i];
  shortx4 s;
  s[0] = (short)f2b(f[0]); s[1] = (short)f2b(f[1]);
  s[2] = (short)f2b(f[2]); s[3] = (short)f2b(f[3]);
  ((shortx4*)out)[i] = s;
}

// fused transpose-convert of both weights: out[c][r] = bf16(in[r][c])
__global__ void tcvt2(const float* __restrict__ w_qkv,
                      const float* __restrict__ w_out,
                      unsigned short* __restrict__ wqkvt,
                      unsigned short* __restrict__ woutt) {
  __shared__ float tile[32][33];
  const float* in; unsigned short* out; int C, bx;
  if (blockIdx.x < 48) { in = w_qkv; out = wqkvt; C = 1536; bx = blockIdx.x; }
  else { in = w_out; out = woutt; C = 512; bx = blockIdx.x - 48; }
  const int R = 512;
  int tx = threadIdx.x & 31, ty = threadIdx.x >> 5;
  int r0 = blockIdx.y * 32, c0 = bx * 32;
#pragma unroll
  for (int i = 0; i < 4; i++) {
    int rr = ty + i * 8;
    tile[rr][tx] = in[(size_t)(r0 + rr) * C + c0 + tx];
  }
  __syncthreads();
#pragma unroll
  for (int i = 0; i < 4; i++) {
    int rr = ty + i * 8;
    out[(size_t)(c0 + rr) * R + r0 + tx] = f2b(tile[tx][rr]);
  }
}

// ---------------------------------------------------------------- QKV GEMM
// C = A * Bt^T. A [8192][512], Bt [1536][512]. 128x128 tile, BK=32, dbuf.
// grid (12,64) = 768 blocks, 3/CU co-resident. ALL outputs fragment-major:
//   q,k: per bh [2048/16 tiles][kc(2)][lane(64)][8]   (identical packing)
//   v:   sigma-permuted V^T per bh [2048/64][b(4)][kc(2)][lane][8]
__global__ __launch_bounds__(256, 3) void gemm_qkv(
    const unsigned short* __restrict__ A, const unsigned short* __restrict__ Bt,
    unsigned short* __restrict__ qf, unsigned short* __restrict__ kf,
    unsigned short* __restrict__ vf) {
  __shared__ __align__(16) unsigned short smem[17408];  // 34816 B
  const int tid = threadIdx.x;
  const int lane = tid & 63, wid = tid >> 6;
  const int g = lane >> 4, r = lane & 15;
  const int m0 = blockIdx.y * 128, n0 = blockIdx.x * 128;
  const int wm = (wid & 1) * 64, wn = (wid >> 1) * 64;
  const int K = 512;

  floatx4 acc[4][4] = {};

  int rowA[2], kbA[2];
#pragma unroll
  for (int i = 0; i < 2; i++) {
    int c = i * 256 + tid;
    rowA[i] = c >> 2;
    kbA[i] = (c & 3) ^ ((rowA[i] >> 1) & 3);
  }

#define STAGE_G(kt, b)                                                           \
  {                                                                              \
    _Pragma("unroll") for (int i = 0; i < 2; i++) {                              \
      GLD_LDS16(A + (size_t)(m0 + rowA[i]) * K + (kt) + kbA[i] * 8,              \
                (char*)smem + (b)*8192 + i * 4096 + wid * 1024);                 \
      GLD_LDS16(Bt + (size_t)(n0 + rowA[i]) * K + (kt) + kbA[i] * 8,             \
                (char*)smem + 16384 + (b)*8192 + i * 4096 + wid * 1024);         \
    }                                                                            \
  }

  STAGE_G(0, 0)
  for (int it = 0; it < 16; it++) {
    const int buf = it & 1;
    __syncthreads();
    if (it + 1 < 16) STAGE_G((it + 1) * 32, buf ^ 1)
    const unsigned short* Xs = smem + buf * 4096;
    const unsigned short* Ws = smem + 8192 + buf * 4096;
    bf16x8 a[4], b[4];
#pragma unroll
    for (int t = 0; t < 4; t++) {
      int rw = wm + t * 16 + r;
      a[t] = *(const bf16x8*)(Xs + rw * 32 + (g ^ ((rw >> 1) & 3)) * 8);
      int rb = wn + t * 16 + r;
      b[t] = *(const bf16x8*)(Ws + rb * 32 + (g ^ ((rb >> 1) & 3)) * 8);
    }
#pragma unroll
    for (int mt = 0; mt < 4; mt++)
#pragma unroll
      for (int nt = 0; nt < 4; nt++)
        acc[mt][nt] = mfma16(a[mt], b[nt], acc[mt][nt]);
  }
#undef STAGE_G

  const int which = blockIdx.x >> 2;  // 0=q 1=k 2=v (block-uniform)
  if (which == 2) {
    // fragment-major sigma-permuted V^T, 16B register stores
    const int tokbase = m0 + wm;  // 64-aligned
    const int bb = tokbase >> 11, vt = (tokbase & 2047) >> 6;
#pragma unroll
    for (int nt = 0; nt < 4; nt++) {
      int vcol = n0 + wn + nt * 16 + r - 1024;
      int h = vcol >> 6;  // uniform over r
      size_t hb = (size_t)(bb * 8 + h) * 131072 + (size_t)vt * 4096 + nt * 1024 +
                  (g * 16 + r) * 8;
#pragma unroll
      for (int kc = 0; kc < 2; kc++) {
        union { unsigned u[4]; shortx8 v; } w;
        w.u[0] = pk2(acc[2 * kc][nt][0], acc[2 * kc][nt][1]);
        w.u[1] = pk2(acc[2 * kc][nt][2], acc[2 * kc][nt][3]);
        w.u[2] = pk2(acc[2 * kc + 1][nt][0], acc[2 * kc + 1][nt][1]);
        w.u[3] = pk2(acc[2 * kc + 1][nt][2], acc[2 * kc + 1][nt][3]);
        *(shortx8*)(vf + hb + kc * 512) = w.v;
      }
    }
  } else {
    const float sc = (which == 0) ? QSCALE : 1.f;
    unsigned short* dst = (which == 0) ? qf : kf;
    __syncthreads();
#pragma unroll
    for (int mt = 0; mt < 4; mt++)
#pragma unroll
      for (int nt = 0; nt < 4; nt++) {
        int col = wn + nt * 16 + r;
#pragma unroll
        for (int e = 0; e < 4; e++)
          smem[(wm + mt * 16 + g * 4 + e) * 136 + col] = f2b(acc[mt][nt][e] * sc);
      }
    __syncthreads();
#pragma unroll
    for (int it = 0; it < 8; it++) {
      int c = it * 256 + tid;
      int row = c >> 4, cc = c & 15;
      shortx8 v = *(const shortx8*)(smem + row * 136 + cc * 8);
      int gq = n0 + cc * 8;            // qkv col (q:0-511, k:512-1023)
      int h = (gq >> 6) & 7, d0 = gq & 63;
      int kc = d0 >> 5, gp = (d0 >> 3) & 3;
      int tok = m0 + row, bb = tok >> 11, n = tok & 2047;
      *(shortx8*)(dst + (size_t)(bb * 8 + h) * 131072 + (n >> 4) * 1024 +
                  kc * 512 + (gp * 16 + (n & 15)) * 8) = v;
    }
  }
}

// ---------------------------------------------------------------- out GEMM
// C = A * Bt^T + bias. A [8192][512] bf16, Bt [512][512] bf16, out fp32.
// 64x128 tile, BK=32, dbuf. grid (4,128) = 512 blocks, 2/CU.
__global__ __launch_bounds__(256, 2) void gemm_out(
    const unsigned short* __restrict__ A, const unsigned short* __restrict__ Bt,
    float* __restrict__ outF, const float* __restrict__ bias) {
  __shared__ __align__(16) unsigned short smem[16896];  // 33792 B
  const int tid = threadIdx.x;
  const int lane = tid & 63, wid = tid >> 6;
  const int g = lane >> 4, r = lane & 15;
  const int m0 = blockIdx.y * 64, n0 = blockIdx.x * 128;
  const int wn = wid * 32;
  const int K = 512;

  floatx4 acc[4][2] = {};

  const int rA = tid >> 2, kA = (tid & 3) ^ ((rA >> 1) & 3);  // A: 1 chunk
  int rB[2], kB[2];
#pragma unroll
  for (int i = 0; i < 2; i++) {
    int c = i * 256 + tid;
    rB[i] = c >> 2;
    kB[i] = (c & 3) ^ ((rB[i] >> 1) & 3);
  }

#define STAGE_O(kt, b)                                                           \
  {                                                                              \
    GLD_LDS16(A + (size_t)(m0 + rA) * K + (kt) + kA * 8,                         \
              (char*)smem + (b)*4096 + wid * 1024);                              \
    _Pragma("unroll") for (int i = 0; i < 2; i++)                                \
        GLD_LDS16(Bt + (size_t)(n0 + rB[i]) * K + (kt) + kB[i] * 8,              \
                  (char*)smem + 8192 + (b)*8192 + i * 4096 + wid * 1024);        \
  }

  STAGE_O(0, 0)
  for (int it = 0; it < 16; it++) {
    const int buf = it & 1;
    __syncthreads();
    if (it + 1 < 16) STAGE_O((it + 1) * 32, buf ^ 1)
    const unsigned short* Xs = smem + buf * 2048;
    const unsigned short* Ws = smem + 4096 + buf * 4096;
    bf16x8 a[4], b[2];
#pragma unroll
    for (int t = 0; t < 4; t++) {
      int rw = t * 16 + r;
      a[t] = *(const bf16x8*)(Xs + rw * 32 + (g ^ ((rw >> 1) & 3)) * 8);
    }
#pragma unroll
    for (int t = 0; t < 2; t++) {
      int rb = wn + t * 16 + r;
      b[t] = *(const bf16x8*)(Ws + rb * 32 + (g ^ ((rb >> 1) & 3)) * 8);
    }
#pragma unroll
    for (int mt = 0; mt < 4; mt++)
#pragma unroll
      for (int bt = 0; bt < 2; bt++)
        acc[mt][bt] = mfma16(a[mt], b[bt], acc[mt][bt]);
  }
#undef STAGE_O

  float* ftile = (float*)smem;  // 64 x 132
  __syncthreads();
#pragma unroll
  for (int mt = 0; mt < 4; mt++)
#pragma unroll
    for (int bt = 0; bt < 2; bt++)
#pragma unroll
      for (int e = 0; e < 4; e++)
        ftile[(mt * 16 + g * 4 + e) * 132 + wn + bt * 16 + r] = acc[mt][bt][e];
  __syncthreads();
#pragma unroll
  for (int it = 0; it < 8; it++) {
    int c = it * 256 + tid;
    int lr = c >> 5, cc = c & 31;
    floatx4 v = *(const floatx4*)(ftile + lr * 132 + cc * 4);
    int col = n0 + cc * 4;
    v += *(const floatx4*)(bias + col);
    *(floatx4*)(outF + (size_t)(m0 + lr) * 512 + col) = v;
  }
}

// ---------------------------------------------------------------- flash attention
// grid (16,32) = 512 blocks (2/CU), LB(256,2). 4 waves x 32 q rows, each wave
// sweeps ALL 2048 kv independently: ZERO LDS / ZERO barriers in the K-loop.
// All operands fragment-major -> every load is a coalesced lane-linear
// dwordx4. No-max softmax; l via in-lane VALU sums (+ end shuffle reduce);
// per-column S->exp2->pack->PV pipeline keeps live registers ~160 (no spill).
__global__ __launch_bounds__(256, 2) void attn(
    const unsigned short* __restrict__ qf, const unsigned short* __restrict__ kf,
    const unsigned short* __restrict__ vf, unsigned short* __restrict__ ao) {
  __shared__ __align__(16) unsigned short Osm[4][32 * 72];  // 18432 B
  const int tid = threadIdx.x, lane = tid & 63, wid = tid >> 6;
  const int g = lane >> 4, r = lane & 15;
  const int bh = blockIdx.y;
  const size_t fbase = (size_t)bh * 131072;
  const unsigned short* kb = kf + fbase;
  const unsigned short* vb = vf + fbase;
  const int q0 = blockIdx.x * 128 + wid * 32;
  const int qt0 = q0 >> 4;

  // Q fragments (B operand), frag-major lane-linear
  bf16x8 bq[2][2];
#pragma unroll
  for (int nt = 0; nt < 2; nt++)
#pragma unroll
    for (int kc = 0; kc < 2; kc++)
      bq[nt][kc] = *(const bf16x8*)(qf + fbase + (size_t)(qt0 + nt) * 1024 +
                                    kc * 512 + lane * 8);

  floatx4 o[2][4] = {};        // [q-block nt][d-block b], C layout
  float lsum[2] = {0.f, 0.f};  // partial row sums (this lane's g-slice)

  for (int s = 0; s < 32; s++) {
    const size_t kt = (size_t)s * 4096;
    bf16x8 ak[4][2], bv[4][2];
#pragma unroll
    for (int mt = 0; mt < 4; mt++)
#pragma unroll
      for (int kc = 0; kc < 2; kc++)
        ak[mt][kc] = *(const bf16x8*)(kb + kt + mt * 1024 + kc * 512 + lane * 8);
#pragma unroll
    for (int b = 0; b < 4; b++)
#pragma unroll
      for (int kc = 0; kc < 2; kc++)
        bv[b][kc] = *(const bf16x8*)(vb + kt + b * 1024 + kc * 512 + lane * 8);

#pragma unroll
    for (int nt = 0; nt < 2; nt++) {
      // S^T column [kv 64][q 16]: col=q(r), row=kv(g*4+e + 16*mt)
      floatx4 st[4] = {};
#pragma unroll
      for (int kc = 0; kc < 2; kc++)
#pragma unroll
        for (int mt = 0; mt < 4; mt++)
          st[mt] = mfma16(ak[mt][kc], bq[nt][kc], st[mt]);

      // p = exp2(s); in-lane l partial sum; pack to A-frags (sigma matches V)
      float p[4][4];
#pragma unroll
      for (int mt = 0; mt < 4; mt++)
#pragma unroll
        for (int e = 0; e < 4; e++) p[mt][e] = fexp2(st[mt][e]);
      lsum[nt] += ((p[0][0] + p[0][1]) + (p[0][2] + p[0][3])) +
                  ((p[1][0] + p[1][1]) + (p[1][2] + p[1][3])) +
                  ((p[2][0] + p[2][1]) + (p[2][2] + p[2][3])) +
                  ((p[3][0] + p[3][1]) + (p[3][2] + p[3][3]));
      bf16x8 ap[2];
#pragma unroll
      for (int kc = 0; kc < 2; kc++) {
        union { unsigned u[4]; bf16x8 v; } w;
        w.u[0] = pk2(p[2 * kc][0], p[2 * kc][1]);
        w.u[1] = pk2(p[2 * kc][2], p[2 * kc][3]);
        w.u[2] = pk2(p[2 * kc + 1][0], p[2 * kc + 1][1]);
        w.u[3] = pk2(p[2 * kc + 1][2], p[2 * kc + 1][3]);
        ap[kc] = w.v;
      }

      // O_col += P_col * V
#pragma unroll
      for (int kc = 0; kc < 2; kc++)
#pragma unroll
        for (int b = 0; b < 4; b++)
          o[nt][b] = mfma16(ap[kc], bv[b][kc], o[nt][b]);
    }
  }

  // full row sums: reduce the 4 g-slices
#pragma unroll
  for (int nt = 0; nt < 2; nt++) {
    lsum[nt] += __shfl_xor(lsum[nt], 16);
    lsum[nt] += __shfl_xor(lsum[nt], 32);
  }

  // normalize + per-wave LDS transpose + coalesced store
#pragma unroll
  for (int nt = 0; nt < 2; nt++) {
    float il[4];
#pragma unroll
    for (int e = 0; e < 4; e++) il[e] = 1.f / __shfl(lsum[nt], g * 4 + e);
#pragma unroll
    for (int b = 0; b < 4; b++)
#pragma unroll
      for (int e = 0; e < 4; e++)
        Osm[wid][(nt * 16 + g * 4 + e) * 72 + b * 16 + r] =
            f2b(o[nt][b][e] * il[e]);
  }
  __syncthreads();
  const int bb = bh >> 3, h = bh & 7;
#pragma unroll
  for (int it = 0; it < 4; it++) {
    int c = it * 256 + tid;
    int row = c >> 3, cc = c & 7;
    int w = row >> 5, r5 = row & 31;
    shortx8 v = *(const shortx8*)(&Osm[w][r5 * 72 + cc * 8]);
    int tok = blockIdx.x * 128 + row;
    *(shortx8*)(ao + ((size_t)(bb * 2048 + tok)) * 512 + h * 64 + cc * 8) = v;
  }
}

// ---------------------------------------------------------------- launcher
extern "C" void kernel_launch(void* const* d_in, const int* in_sizes, int n_in,
                              void* d_out, int out_size, void* d_ws, size_t ws_size,
                              hipStream_t stream) {
  const float* x = (const float*)d_in[0];      // [4,2048,512]
  const float* w_qkv = (const float*)d_in[1];  // [512,1536]
  const float* w_out = (const float*)d_in[2];  // [512,512]
  const float* b_out = (const float*)d_in[3];  // [512]
  float* out = (float*)d_out;                  // [4,2048,512] fp32

  unsigned short* wsp = (unsigned short*)d_ws;
  unsigned short* xb = wsp;                            // 8192*512
  unsigned short* wqkvt = xb + (size_t)8192 * 512;     // 1536*512
  unsigned short* woutt = wqkvt + (size_t)1536 * 512;  // 512*512
  unsigned short* qf = woutt + (size_t)512 * 512;      // frag-major per bh
  unsigned short* kf = qf + (size_t)32 * 2048 * 64;    // frag-major per bh
  unsigned short* vf = kf + (size_t)32 * 2048 * 64;    // frag-major sigma V^T
  unsigned short* ao = vf + (size_t)32 * 2048 * 64;    // [8192][512]

  cvt_f32_bf16<<<4096, 256, 0, stream>>>(x, xb, 8192 * 512 / 4);
  tcvt2<<<dim3(64, 16), 256, 0, stream>>>(w_qkv, w_out, wqkvt, woutt);
  gemm_qkv<<<dim3(12, 64), 256, 0, stream>>>(xb, wqkvt, qf, kf, vf);
  attn<<<dim3(16, 32), 256, 0, stream>>>(qf, kf, vf, ao);
  gemm_out<<<dim3(4, 128), 256, 0, stream>>>(ao, woutt, out, b_out);
}

// Round 8
// 159.481 us; speedup vs baseline: 1.1818x; 1.1818x over previous
//
#include <hip/hip_runtime.h>
#include <hip/hip_bf16.h>
#include <cstdint>

#define DEV __device__ __forceinline__

typedef __attribute__((ext_vector_type(8))) __bf16 bf16x8;
typedef __attribute__((ext_vector_type(4))) float floatx4;
typedef __attribute__((ext_vector_type(4))) short shortx4;
typedef __attribute__((ext_vector_type(8))) short shortx8;

// 0.125 (= dim_head^-0.5) * log2(e): fold scale AND base-2 conversion into Q.
constexpr float QSCALE = 0.18033688011112042f;

DEV unsigned short f2b(float f) {
  union { float f; unsigned u; } v; v.f = f;
  return (unsigned short)((v.u + 0x7fffu + ((v.u >> 16) & 1u)) >> 16);  // RTNE
}

#if defined(__has_builtin) && __has_builtin(__builtin_amdgcn_cvt_pk_bf16_f32)
DEV unsigned pk2(float a, float b) {
  typedef __attribute__((ext_vector_type(2))) __bf16 bf2;
  union { bf2 v; unsigned u; } u;
  u.v = __builtin_amdgcn_cvt_pk_bf16_f32(a, b);
  return u.u;
}
#else
DEV unsigned pk2(float a, float b) {
  return (unsigned)f2b(a) | ((unsigned)f2b(b) << 16);
}
#endif

#if defined(__has_builtin) && __has_builtin(__builtin_amdgcn_exp2f)
DEV float fexp2(float x) { return __builtin_amdgcn_exp2f(x); }
#else
DEV float fexp2(float x) { return exp2f(x); }
#endif

DEV floatx4 mfma16(bf16x8 a, bf16x8 b, floatx4 c) {
  return __builtin_amdgcn_mfma_f32_16x16x32_bf16(a, b, c, 0, 0, 0);
}

#define GLD_LDS16(gp, lp)                                                          \
  __builtin_amdgcn_global_load_lds(                                                \
      (const __attribute__((address_space(1))) void*)(gp),                         \
      (__attribute__((address_space(3))) void*)(lp), 16, 0, 0)

// ---------------------------------------------------------------- weights tcvt
// fused transpose-convert of both weights: out[c][r] = bf16(in[r][c])
__global__ void tcvt2(const float* __restrict__ w_qkv,
                      const float* __restrict__ w_out,
                      unsigned short* __restrict__ wqkvt,
                      unsigned short* __restrict__ woutt) {
  __shared__ float tile[32][33];
  const float* in; unsigned short* out; int C, bx;
  if (blockIdx.x < 48) { in = w_qkv; out = wqkvt; C = 1536; bx = blockIdx.x; }
  else { in = w_out; out = woutt; C = 512; bx = blockIdx.x - 48; }
  const int R = 512;
  int tx = threadIdx.x & 31, ty = threadIdx.x >> 5;
  int r0 = blockIdx.y * 32, c0 = bx * 32;
#pragma unroll
  for (int i = 0; i < 4; i++) {
    int rr = ty + i * 8;
    tile[rr][tx] = in[(size_t)(r0 + rr) * C + c0 + tx];
  }
  __syncthreads();
#pragma unroll
  for (int i = 0; i < 4; i++) {
    int rr = ty + i * 8;
    out[(size_t)(c0 + rr) * R + r0 + tx] = f2b(tile[tx][rr]);
  }
}

// ---------------------------------------------------------------- QKV GEMM
// C = x * Bt^T. x [8192][512] FP32 (staged raw via global_load_lds, converted
// to bf16 during fragment build -> no separate cvt kernel). Bt [1536][512]
// bf16. 128x128 tile, BK=32, dbuf. grid (12,64) = 768 blocks, 3/CU.
// Outputs all FRAGMENT-MAJOR:
//   q,k: per bh [2048/16 tiles][kc(2)][lane(64)][8]
//   v:   sigma-permuted V^T per bh [2048/64][b(4)][kc(2)][lane][8]
__global__ __launch_bounds__(256, 3) void gemm_qkv(
    const float* __restrict__ x, const unsigned short* __restrict__ Bt,
    unsigned short* __restrict__ qf, unsigned short* __restrict__ kf,
    unsigned short* __restrict__ vf) {
  __shared__ __align__(16) char smem[49152];  // A fp32 2x16KB | B bf16 2x8KB
  const int tid = threadIdx.x;
  const int lane = tid & 63, wid = tid >> 6;
  const int g = lane >> 4, r = lane & 15;
  const int m0 = blockIdx.y * 128, n0 = blockIdx.x * 128;
  const int wm = (wid & 1) * 64, wn = (wid >> 1) * 64;

  floatx4 acc[4][4] = {};

  // A staging: 16B fp32 chunks, 8/row, XOR-swizzled slots
  int rA[4], kA[4];
#pragma unroll
  for (int i = 0; i < 4; i++) {
    int c = i * 256 + tid;
    rA[i] = c >> 3;
    kA[i] = (c & 7) ^ (rA[i] & 7);
  }
  // B staging: 16B bf16 chunks, 4/row
  int rB[2], kB[2];
#pragma unroll
  for (int i = 0; i < 2; i++) {
    int c = i * 256 + tid;
    rB[i] = c >> 2;
    kB[i] = (c & 3) ^ ((rB[i] >> 1) & 3);
  }

#define STAGE_G(kt, b)                                                           \
  {                                                                              \
    _Pragma("unroll") for (int i = 0; i < 4; i++)                                \
        GLD_LDS16(x + (size_t)(m0 + rA[i]) * 512 + (kt) + kA[i] * 4,             \
                  smem + (b)*16384 + i * 4096 + wid * 1024);                     \
    _Pragma("unroll") for (int i = 0; i < 2; i++)                                \
        GLD_LDS16(Bt + (size_t)(n0 + rB[i]) * 512 + (kt) + kB[i] * 8,            \
                  smem + 32768 + (b)*8192 + i * 4096 + wid * 1024);              \
  }

  STAGE_G(0, 0)
  for (int it = 0; it < 16; it++) {
    const int buf = it & 1;
    __syncthreads();
    if (it + 1 < 16) STAGE_G((it + 1) * 32, buf ^ 1)
    const float* Af = (const float*)(smem + buf * 16384);
    const unsigned short* Ws = (const unsigned short*)(smem + 32768 + buf * 8192);
    bf16x8 a[4], b[4];
#pragma unroll
    for (int t = 0; t < 4; t++) {
      int rw = wm + t * 16 + r;
      const float* Ar = Af + rw * 32;
      floatx4 f0 = *(const floatx4*)(Ar + (((2 * g)) ^ (rw & 7)) * 4);
      floatx4 f1 = *(const floatx4*)(Ar + (((2 * g + 1)) ^ (rw & 7)) * 4);
      union { unsigned u[4]; bf16x8 v; } w;
      w.u[0] = pk2(f0[0], f0[1]); w.u[1] = pk2(f0[2], f0[3]);
      w.u[2] = pk2(f1[0], f1[1]); w.u[3] = pk2(f1[2], f1[3]);
      a[t] = w.v;
      int rb = wn + t * 16 + r;
      b[t] = *(const bf16x8*)(Ws + rb * 32 + (g ^ ((rb >> 1) & 3)) * 8);
    }
#pragma unroll
    for (int mt = 0; mt < 4; mt++)
#pragma unroll
      for (int nt = 0; nt < 4; nt++)
        acc[mt][nt] = mfma16(a[mt], b[nt], acc[mt][nt]);
  }
#undef STAGE_G

  const int which = blockIdx.x >> 2;  // 0=q 1=k 2=v (block-uniform)
  if (which == 2) {
    const int tokbase = m0 + wm;  // 64-aligned
    const int bb = tokbase >> 11, vt = (tokbase & 2047) >> 6;
#pragma unroll
    for (int nt = 0; nt < 4; nt++) {
      int vcol = n0 + wn + nt * 16 + r - 1024;
      int h = vcol >> 6;  // uniform over r
      size_t hb = (size_t)(bb * 8 + h) * 131072 + (size_t)vt * 4096 + nt * 1024 +
                  (g * 16 + r) * 8;
#pragma unroll
      for (int kc = 0; kc < 2; kc++) {
        union { unsigned u[4]; shortx8 v; } w;
        w.u[0] = pk2(acc[2 * kc][nt][0], acc[2 * kc][nt][1]);
        w.u[1] = pk2(acc[2 * kc][nt][2], acc[2 * kc][nt][3]);
        w.u[2] = pk2(acc[2 * kc + 1][nt][0], acc[2 * kc + 1][nt][1]);
        w.u[3] = pk2(acc[2 * kc + 1][nt][2], acc[2 * kc + 1][nt][3]);
        *(shortx8*)(vf + hb + kc * 512) = w.v;
      }
    }
  } else {
    const float sc = (which == 0) ? QSCALE : 1.f;
    unsigned short* dst = (which == 0) ? qf : kf;
    unsigned short* sm = (unsigned short*)smem;  // 128 x 136
    __syncthreads();
#pragma unroll
    for (int mt = 0; mt < 4; mt++)
#pragma unroll
      for (int nt = 0; nt < 4; nt++) {
        int col = wn + nt * 16 + r;
#pragma unroll
        for (int e = 0; e < 4; e++)
          sm[(wm + mt * 16 + g * 4 + e) * 136 + col] = f2b(acc[mt][nt][e] * sc);
      }
    __syncthreads();
#pragma unroll
    for (int it = 0; it < 8; it++) {
      int c = it * 256 + tid;
      int row = c >> 4, cc = c & 15;
      shortx8 v = *(const shortx8*)(sm + row * 136 + cc * 8);
      int gq = n0 + cc * 8;
      int h = (gq >> 6) & 7, d0 = gq & 63;
      int kc = d0 >> 5, gp = (d0 >> 3) & 3;
      int tok = m0 + row, bb = tok >> 11, n = tok & 2047;
      *(shortx8*)(dst + (size_t)(bb * 8 + h) * 131072 + (n >> 4) * 1024 +
                  kc * 512 + (gp * 16 + (n & 15)) * 8) = v;
    }
  }
}

// ---------------------------------------------------------------- out GEMM
// C = A * Bt^T + bias. A [8192][512] bf16, Bt [512][512] bf16, out fp32.
// 64x128 tile, BK=32, dbuf. grid (4,128) = 512 blocks, 2/CU.
__global__ __launch_bounds__(256, 2) void gemm_out(
    const unsigned short* __restrict__ A, const unsigned short* __restrict__ Bt,
    float* __restrict__ outF, const float* __restrict__ bias) {
  __shared__ __align__(16) unsigned short smem[16896];  // 33792 B
  const int tid = threadIdx.x;
  const int lane = tid & 63, wid = tid >> 6;
  const int g = lane >> 4, r = lane & 15;
  const int m0 = blockIdx.y * 64, n0 = blockIdx.x * 128;
  const int wn = wid * 32;
  const int K = 512;

  floatx4 acc[4][2] = {};

  const int rA = tid >> 2, kA = (tid & 3) ^ ((rA >> 1) & 3);  // A: 1 chunk
  int rB[2], kB[2];
#pragma unroll
  for (int i = 0; i < 2; i++) {
    int c = i * 256 + tid;
    rB[i] = c >> 2;
    kB[i] = (c & 3) ^ ((rB[i] >> 1) & 3);
  }

#define STAGE_O(kt, b)                                                           \
  {                                                                              \
    GLD_LDS16(A + (size_t)(m0 + rA) * K + (kt) + kA * 8,                         \
              (char*)smem + (b)*4096 + wid * 1024);                              \
    _Pragma("unroll") for (int i = 0; i < 2; i++)                                \
        GLD_LDS16(Bt + (size_t)(n0 + rB[i]) * K + (kt) + kB[i] * 8,              \
                  (char*)smem + 8192 + (b)*8192 + i * 4096 + wid * 1024);        \
  }

  STAGE_O(0, 0)
  for (int it = 0; it < 16; it++) {
    const int buf = it & 1;
    __syncthreads();
    if (it + 1 < 16) STAGE_O((it + 1) * 32, buf ^ 1)
    const unsigned short* Xs = smem + buf * 2048;
    const unsigned short* Ws = smem + 4096 + buf * 4096;
    bf16x8 a[4], b[2];
#pragma unroll
    for (int t = 0; t < 4; t++) {
      int rw = t * 16 + r;
      a[t] = *(const bf16x8*)(Xs + rw * 32 + (g ^ ((rw >> 1) & 3)) * 8);
    }
#pragma unroll
    for (int t = 0; t < 2; t++) {
      int rb = wn + t * 16 + r;
      b[t] = *(const bf16x8*)(Ws + rb * 32 + (g ^ ((rb >> 1) & 3)) * 8);
    }
#pragma unroll
    for (int mt = 0; mt < 4; mt++)
#pragma unroll
      for (int bt = 0; bt < 2; bt++)
        acc[mt][bt] = mfma16(a[mt], b[bt], acc[mt][bt]);
  }
#undef STAGE_O

  float* ftile = (float*)smem;  // 64 x 132
  __syncthreads();
#pragma unroll
  for (int mt = 0; mt < 4; mt++)
#pragma unroll
    for (int bt = 0; bt < 2; bt++)
#pragma unroll
      for (int e = 0; e < 4; e++)
        ftile[(mt * 16 + g * 4 + e) * 132 + wn + bt * 16 + r] = acc[mt][bt][e];
  __syncthreads();
#pragma unroll
  for (int it = 0; it < 8; it++) {
    int c = it * 256 + tid;
    int lr = c >> 5, cc = c & 31;
    floatx4 v = *(const floatx4*)(ftile + lr * 132 + cc * 4);
    int col = n0 + cc * 4;
    v += *(const floatx4*)(bias + col);
    *(floatx4*)(outF + (size_t)(m0 + lr) * 512 + col) = v;
  }
}

// ---------------------------------------------------------------- flash attention
// grid (32 bh, 16 qtile): flat%8 = bh%8 -> each bh's 512KB KV set pins to one
// XCD L2. LB(256,2). 4 waves x 32 q rows; each wave sweeps all 2048 kv
// independently: ZERO LDS/barriers in the K-loop. EXPLICIT register
// double-buffer (2x(K+V) = 128 VGPRs) forces true software pipelining --
// loads for tile s+1 issue before tile-s compute, drained by vmcnt at next
// use (round-7's 60-VGPR latency collapse fixed; round-5's 64q spill avoided).
__global__ __launch_bounds__(256, 2) void attn(
    const unsigned short* __restrict__ qf, const unsigned short* __restrict__ kf,
    const unsigned short* __restrict__ vf, unsigned short* __restrict__ ao) {
  __shared__ __align__(16) unsigned short Osm[4][32 * 72];  // 18432 B
  const int tid = threadIdx.x, lane = tid & 63, wid = tid >> 6;
  const int g = lane >> 4, r = lane & 15;
  const int bh = blockIdx.x;
  const size_t fbase = (size_t)bh * 131072;
  const unsigned short* kb = kf + fbase;
  const unsigned short* vb = vf + fbase;
  const int q0 = blockIdx.y * 128 + wid * 32;
  const int qt0 = q0 >> 4;

  bf16x8 bq[2][2];
#pragma unroll
  for (int nt = 0; nt < 2; nt++)
#pragma unroll
    for (int kc = 0; kc < 2; kc++)
      bq[nt][kc] = *(const bf16x8*)(qf + fbase + (size_t)(qt0 + nt) * 1024 +
                                    kc * 512 + lane * 8);

  floatx4 o[2][4] = {};
  float lsum[2] = {0.f, 0.f};

  bf16x8 akA[4][2], bvA[4][2], akB[4][2], bvB[4][2];

#define LOADKV(ak_, bv_, s_)                                                     \
  {                                                                              \
    const size_t kt = (size_t)(s_)*4096;                                         \
    _Pragma("unroll") for (int mt = 0; mt < 4; mt++)                             \
      _Pragma("unroll") for (int kc = 0; kc < 2; kc++)                           \
          ak_[mt][kc] = *(const bf16x8*)(kb + kt + mt * 1024 + kc * 512 +        \
                                         lane * 8);                              \
    _Pragma("unroll") for (int b = 0; b < 4; b++)                                \
      _Pragma("unroll") for (int kc = 0; kc < 2; kc++)                           \
          bv_[b][kc] = *(const bf16x8*)(vb + kt + b * 1024 + kc * 512 +          \
                                        lane * 8);                               \
  }

#define STEP(akC, bvC, akN, bvN, sn, cond)                                       \
  {                                                                              \
    if (cond) LOADKV(akN, bvN, sn)                                               \
    _Pragma("unroll") for (int nt = 0; nt < 2; nt++) {                           \
      floatx4 st[4] = {};                                                        \
      _Pragma("unroll") for (int kc = 0; kc < 2; kc++)                           \
        _Pragma("unroll") for (int mt = 0; mt < 4; mt++)                         \
            st[mt] = mfma16(akC[mt][kc], bq[nt][kc], st[mt]);                    \
      float p[4][4];                                                             \
      _Pragma("unroll") for (int mt = 0; mt < 4; mt++)                           \
        _Pragma("unroll") for (int e = 0; e < 4; e++)                            \
            p[mt][e] = fexp2(st[mt][e]);                                         \
      lsum[nt] += ((p[0][0] + p[0][1]) + (p[0][2] + p[0][3])) +                  \
                  ((p[1][0] + p[1][1]) + (p[1][2] + p[1][3])) +                  \
                  ((p[2][0] + p[2][1]) + (p[2][2] + p[2][3])) +                  \
                  ((p[3][0] + p[3][1]) + (p[3][2] + p[3][3]));                   \
      bf16x8 ap[2];                                                              \
      _Pragma("unroll") for (int kc = 0; kc < 2; kc++) {                         \
        union { unsigned u[4]; bf16x8 v; } w;                                    \
        w.u[0] = pk2(p[2 * kc][0], p[2 * kc][1]);                                \
        w.u[1] = pk2(p[2 * kc][2], p[2 * kc][3]);                                \
        w.u[2] = pk2(p[2 * kc + 1][0], p[2 * kc + 1][1]);                        \
        w.u[3] = pk2(p[2 * kc + 1][2], p[2 * kc + 1][3]);                        \
        ap[kc] = w.v;                                                            \
      }                                                                          \
      _Pragma("unroll") for (int kc = 0; kc < 2; kc++)                           \
        _Pragma("unroll") for (int b = 0; b < 4; b++)                            \
            o[nt][b] = mfma16(ap[kc], bvC[b][kc], o[nt][b]);                     \
    }                                                                            \
  }

  LOADKV(akA, bvA, 0)
  for (int s2 = 0; s2 < 16; s2++) {
    STEP(akA, bvA, akB, bvB, 2 * s2 + 1, true)
    STEP(akB, bvB, akA, bvA, 2 * s2 + 2, s2 < 15)
  }
#undef STEP
#undef LOADKV

  // row sums: reduce the 4 g-slices
#pragma unroll
  for (int nt = 0; nt < 2; nt++) {
    lsum[nt] += __shfl_xor(lsum[nt], 16);
    lsum[nt] += __shfl_xor(lsum[nt], 32);
  }

  // normalize + per-wave LDS transpose + coalesced store
#pragma unroll
  for (int nt = 0; nt < 2; nt++) {
    float il[4];
#pragma unroll
    for (int e = 0; e < 4; e++) il[e] = 1.f / __shfl(lsum[nt], g * 4 + e);
#pragma unroll
    for (int b = 0; b < 4; b++)
#pragma unroll
      for (int e = 0; e < 4; e++)
        Osm[wid][(nt * 16 + g * 4 + e) * 72 + b * 16 + r] =
            f2b(o[nt][b][e] * il[e]);
  }
  __syncthreads();
  const int bb = bh >> 3, h = bh & 7;
#pragma unroll
  for (int it = 0; it < 4; it++) {
    int c = it * 256 + tid;
    int row = c >> 3, cc = c & 7;
    int w = row >> 5, r5 = row & 31;
    shortx8 v = *(const shortx8*)(&Osm[w][r5 * 72 + cc * 8]);
    int tok = blockIdx.y * 128 + row;
    *(shortx8*)(ao + ((size_t)(bb * 2048 + tok)) * 512 + h * 64 + cc * 8) = v;
  }
}

// ---------------------------------------------------------------- launcher
extern "C" void kernel_launch(void* const* d_in, const int* in_sizes, int n_in,
                              void* d_out, int out_size, void* d_ws, size_t ws_size,
                              hipStream_t stream) {
  const float* x = (const float*)d_in[0];      // [4,2048,512]
  const float* w_qkv = (const float*)d_in[1];  // [512,1536]
  const float* w_out = (const float*)d_in[2];  // [512,512]
  const float* b_out = (const float*)d_in[3];  // [512]
  float* out = (float*)d_out;                  // [4,2048,512] fp32

  unsigned short* wsp = (unsigned short*)d_ws;
  unsigned short* wqkvt = wsp;                         // 1536*512
  unsigned short* woutt = wqkvt + (size_t)1536 * 512;  // 512*512
  unsigned short* qf = woutt + (size_t)512 * 512;      // frag-major per bh
  unsigned short* kf = qf + (size_t)32 * 2048 * 64;    // frag-major per bh
  unsigned short* vf = kf + (size_t)32 * 2048 * 64;    // frag-major sigma V^T
  unsigned short* ao = vf + (size_t)32 * 2048 * 64;    // [8192][512]

  tcvt2<<<dim3(64, 16), 256, 0, stream>>>(w_qkv, w_out, wqkvt, woutt);
  gemm_qkv<<<dim3(12, 64), 256, 0, stream>>>(x, wqkvt, qf, kf, vf);
  attn<<<dim3(32, 16), 256, 0, stream>>>(qf, kf, vf, ao);
  gemm_out<<<dim3(4, 128), 256, 0, stream>>>(ao, woutt, out, b_out);
}